// Round 17
// baseline (580.652 us; speedup 1.0000x reference)
//
#include <hip/hip_runtime.h>
#include <math.h>

#define NN 16384
#define H 128
#define CODE 1024
#define RSTR 132   // f32 red/h2 stride: 132 mod 32 = 4 -> 2-way max bank aliasing

typedef __attribute__((ext_vector_type(8))) short short8;
typedef __attribute__((ext_vector_type(4))) float f32x4;

// ---- ws layout (bytes) ----
#define OFF_WIN   0u
#define OFF_WOUT  262144u
#define OFF_P     524288u       // 4 x [256][128] bf16 (eW1 split), stride 256
#define OFF_N1    786432u       // 4 x [128][256] bf16, stride 512
#define OFF_N2    1048576u      // 4 x [128][128] bf16, stride 256
#define OFF_W2    1179648u      // 4 x [128][128] bf16 eW2^T, stride 256
#define OFF_H     1318912u                   // h   fp32  8388608
#define OFF_HN    (OFF_H + 8388608u)         // hn  fp32  8388608
#define OFF_PBUF  (OFF_HN + 8388608u)        // Pb ping-pong: 2 x 8388608 bf16

__device__ __forceinline__ float silu_fast(float x) {
    float e = __expf(-x);
    return x * __builtin_amdgcn_rcpf(1.0f + e);
}

__device__ __forceinline__ unsigned short f2bf(float f) {
    unsigned int u = __float_as_uint(f);
    u = (u + 0x7FFFu + ((u >> 16) & 1u)) >> 16;
    return (unsigned short)u;
}

__device__ __forceinline__ float bf2f(short s) {
    return __uint_as_float(((unsigned)(unsigned short)s) << 16);
}

__device__ __forceinline__ short8 pack_bf16_8(const float* v) {
    union { unsigned u[4]; short8 s; } r;
    asm("v_cvt_pk_bf16_f32 %0, %1, %2" : "=v"(r.u[0]) : "v"(v[0]), "v"(v[1]));
    asm("v_cvt_pk_bf16_f32 %0, %1, %2" : "=v"(r.u[1]) : "v"(v[2]), "v"(v[3]));
    asm("v_cvt_pk_bf16_f32 %0, %1, %2" : "=v"(r.u[2]) : "v"(v[4]), "v"(v[5]));
    asm("v_cvt_pk_bf16_f32 %0, %1, %2" : "=v"(r.u[3]) : "v"(v[6]), "v"(v[7]));
    return r.s;
}

__device__ __forceinline__ short8 cvtfrag(const float* p) {
    float v[8];
    float4 a = *(const float4*)p;
    float4 b = *(const float4*)(p + 4);
    v[0]=a.x; v[1]=a.y; v[2]=a.z; v[3]=a.w; v[4]=b.x; v[5]=b.y; v[6]=b.z; v[7]=b.w;
    return pack_bf16_8(v);
}

__device__ const int SDX[26] = {-1,-1,-1,-1, 1, 1, 1, 1,  -1,-1,-1,-1, 0,  0, 0, 0, 1, 1, 1, 1,  -1, 1, 0, 0, 0, 0};
__device__ const int SDY[26] = {-1,-1, 1, 1,-1,-1, 1, 1,  -1, 0, 0, 1,-1, -1, 1, 1,-1, 0, 0, 1,   0, 0,-1, 1, 0, 0};
__device__ const int SDZ[26] = {-1, 1,-1, 1,-1, 1,-1, 1,   0,-1, 1, 0,-1,  1,-1, 1, 0,-1, 1, 0,   0, 0, 0, 0,-1, 1};

// transposed bf16 weight images
__global__ void k_prep(const float* __restrict__ W_in, const float* __restrict__ W_out,
                       const float* __restrict__ eW1, const float* __restrict__ nW1,
                       const float* __restrict__ nW2, const float* __restrict__ eW2,
                       char* __restrict__ base) {
    int t = blockIdx.x * 256 + threadIdx.x;
    if (t < 131072) {
        int n = t >> 10, k = t & 1023;
        *(unsigned short*)(base + OFF_WIN + n * 2048 + k * 2) = f2bf(W_in[k * 128 + n]);
        return;
    }
    t -= 131072;
    if (t < 131072) {
        int n = t >> 7, k = t & 127;
        *(unsigned short*)(base + OFF_WOUT + n * 256 + k * 2) = f2bf(W_out[k * 1024 + n]);
        return;
    }
    t -= 131072;
    if (t < 131072) {
        int l = t >> 15, r = t & 32767;
        int jj = r >> 7, k = r & 127;
        const float* W = eW1 + (size_t)l * 257 * 128;
        float v = (jj < 128) ? W[k * 128 + jj] : W[(128 + k) * 128 + (jj - 128)];
        *(unsigned short*)(base + OFF_P + (size_t)l * 65536 + jj * 256 + k * 2) = f2bf(v);
        return;
    }
    t -= 131072;
    if (t < 131072) {
        int l = t >> 15, r = t & 32767;
        int n = r >> 8, k = r & 255;
        *(unsigned short*)(base + OFF_N1 + (size_t)l * 65536 + n * 512 + k * 2) =
            f2bf(nW1[(size_t)l * 256 * 128 + k * 128 + n]);
        return;
    }
    t -= 131072;
    if (t < 65536) {
        int l = t >> 14, r = t & 16383;
        int n = r >> 7, k = r & 127;
        *(unsigned short*)(base + OFF_N2 + (size_t)l * 32768 + n * 256 + k * 2) =
            f2bf(nW2[(size_t)l * 128 * 128 + k * 128 + n]);
        return;
    }
    t -= 65536;
    if (t < 65536) {
        int l = t >> 14, r = t & 16383;
        int n = r >> 7, k = r & 127;
        *(unsigned short*)(base + OFF_W2 + (size_t)l * 32768 + n * 256 + k * 2) =
            f2bf(eW2[(size_t)l * 128 * 128 + k * 128 + n]);
    }
}

// ---------------- h = y @ W_in + b_in (MFMA) ----------------
__global__ __launch_bounds__(256) void k_in_mfma(const float* __restrict__ y,
                                                 const char* __restrict__ imgWin,
                                                 const float* __restrict__ bi,
                                                 float* __restrict__ h) {
    int tid = threadIdx.x, w = tid >> 6, lane = tid & 63;
    int l15 = lane & 15, kg = lane >> 4;
    int m0 = blockIdx.x * 64 + w * 16;
    const float* yr = y + (size_t)(m0 + l15) * CODE;
    f32x4 acc[8];
#pragma unroll
    for (int nt = 0; nt < 8; nt++) { f32x4 z = {0.f,0.f,0.f,0.f}; acc[nt] = z; }
#pragma unroll 4
    for (int ks = 0; ks < 32; ks++) {
        short8 a = cvtfrag(yr + ks * 32 + kg * 8);
        const char* bp = imgWin + ks * 64 + kg * 16;
#pragma unroll
        for (int nt = 0; nt < 8; nt++) {
            short8 b = *(const short8*)(bp + (nt * 16 + l15) * 2048);
            acc[nt] = __builtin_amdgcn_mfma_f32_16x16x32_bf16(a, b, acc[nt], 0, 0, 0);
        }
    }
#pragma unroll
    for (int nt = 0; nt < 8; nt++) {
        int cc = nt * 16 + l15;
        float bb = bi[cc];
#pragma unroll
        for (int r = 0; r < 4; r++)
            h[(size_t)(m0 + kg * 4 + r) * H + cc] = acc[nt][r] + bb;
    }
}

// ---------------- fused LN + P GEMM (layer 0 only) ----------------
__global__ __launch_bounds__(256) void k_lnP(const float* __restrict__ h,
                                             const float* __restrict__ g,
                                             const float* __restrict__ bln,
                                             const char* __restrict__ imgP,
                                             const float* __restrict__ b1,
                                             float* __restrict__ hn,
                                             unsigned short* __restrict__ Pb) {
    int bid = blockIdx.x;
    int rowblk = bid >> 1, nc = bid & 1;
    int tid = threadIdx.x, w = tid >> 6, lane = tid & 63;
    int l15 = lane & 15, kg = lane >> 4;
    int m0 = rowblk * 64 + w * 16;
    int row = m0 + l15;
    const float* hr = h + (size_t)row * H;

    float hv[32];
#pragma unroll
    for (int ks = 0; ks < 4; ks++) {
        float4 a4 = *(const float4*)(hr + ks * 32 + kg * 8);
        float4 b4 = *(const float4*)(hr + ks * 32 + kg * 8 + 4);
        hv[ks*8+0]=a4.x; hv[ks*8+1]=a4.y; hv[ks*8+2]=a4.z; hv[ks*8+3]=a4.w;
        hv[ks*8+4]=b4.x; hv[ks*8+5]=b4.y; hv[ks*8+6]=b4.z; hv[ks*8+7]=b4.w;
    }
    float s = 0.0f;
#pragma unroll
    for (int i = 0; i < 32; i++) s += hv[i];
    s += __shfl_xor(s, 16); s += __shfl_xor(s, 32);
    float mu = s * (1.0f / 128.0f);
    float vs = 0.0f;
#pragma unroll
    for (int i = 0; i < 32; i++) { float d = hv[i] - mu; vs += d * d; }
    vs += __shfl_xor(vs, 16); vs += __shfl_xor(vs, 32);
    float rs = rsqrtf(vs * (1.0f / 128.0f) + 1e-5f);

#pragma unroll
    for (int ks = 0; ks < 4; ks++) {
        float4 g0 = *(const float4*)(g + ks * 32 + kg * 8);
        float4 g1 = *(const float4*)(g + ks * 32 + kg * 8 + 4);
        float4 c0 = *(const float4*)(bln + ks * 32 + kg * 8);
        float4 c1 = *(const float4*)(bln + ks * 32 + kg * 8 + 4);
        hv[ks*8+0] = (hv[ks*8+0]-mu)*rs*g0.x + c0.x;
        hv[ks*8+1] = (hv[ks*8+1]-mu)*rs*g0.y + c0.y;
        hv[ks*8+2] = (hv[ks*8+2]-mu)*rs*g0.z + c0.z;
        hv[ks*8+3] = (hv[ks*8+3]-mu)*rs*g0.w + c0.w;
        hv[ks*8+4] = (hv[ks*8+4]-mu)*rs*g1.x + c1.x;
        hv[ks*8+5] = (hv[ks*8+5]-mu)*rs*g1.y + c1.y;
        hv[ks*8+6] = (hv[ks*8+6]-mu)*rs*g1.z + c1.z;
        hv[ks*8+7] = (hv[ks*8+7]-mu)*rs*g1.w + c1.w;
    }
    if (nc == 0) {
        float* o = hn + (size_t)row * H;
#pragma unroll
        for (int ks = 0; ks < 4; ks++) {
            *(float4*)(o + ks * 32 + kg * 8)     = *(float4*)&hv[ks*8];
            *(float4*)(o + ks * 32 + kg * 8 + 4) = *(float4*)&hv[ks*8+4];
        }
    }
    short8 a[4];
#pragma unroll
    for (int ks = 0; ks < 4; ks++) a[ks] = pack_bf16_8(&hv[ks*8]);

    f32x4 acc[8];
#pragma unroll
    for (int nt = 0; nt < 8; nt++) { f32x4 z = {0.f,0.f,0.f,0.f}; acc[nt] = z; }
#pragma unroll
    for (int ks = 0; ks < 4; ks++) {
        const char* bp = imgP + (size_t)(nc * 128) * 256 + ks * 64 + kg * 16;
#pragma unroll
        for (int nt = 0; nt < 8; nt++) {
            short8 b = *(const short8*)(bp + (nt * 16 + l15) * 256);
            acc[nt] = __builtin_amdgcn_mfma_f32_16x16x32_bf16(a[ks], b, acc[nt], 0, 0, 0);
        }
    }
#pragma unroll
    for (int nt = 0; nt < 8; nt++) {
        int jj = nc * 128 + nt * 16 + l15;
        float add = nc ? b1[nt * 16 + l15] : 0.0f;
#pragma unroll
        for (int r = 0; r < 4; r++)
            Pb[(size_t)(m0 + kg * 4 + r) * 256 + jj] = f2bf(acc[nt][r] + add);
    }
}

// ---------------- FUSED LAYER: full-plane block, 16 waves (4 M-tiles x 4 groups) ----------------
// grid = 256 = 1 block/CU; 4 waves/SIMD (body ~84 regs <= 128 budget -> no spill).
__global__ __launch_bounds__(1024) void k_layer(
        const unsigned short* __restrict__ Pb, const char* __restrict__ imgW2,
        const float* __restrict__ w256f, const float* __restrict__ b2,
        float* __restrict__ hn, const char* __restrict__ imgN1,
        const float* __restrict__ nb1, const char* __restrict__ imgN2,
        const float* __restrict__ nb2, float* __restrict__ h, int last,
        const float* __restrict__ lngn, const float* __restrict__ lnbn,
        const char* __restrict__ imgPn, const float* __restrict__ b1n,
        unsigned short* __restrict__ PbOut) {
    __shared__ __align__(16) char sP1[3 * 16384];   // planes -> red f32 -> h2 f32
    __shared__ __align__(16) char sB[32768];        // eW2 -> sM bf16
    float* red = (float*)sP1;
    float* h2  = (float*)sP1;
    char*  sM  = sB;

    int tid = threadIdx.x, wv = tid >> 6, lane = tid & 63;
    int mt = wv & 3, grp = wv >> 2;                 // mt 0..3, grp 0..3
    int l15 = lane & 15, kg = lane >> 4;
    int n0 = blockIdx.x * 64;
    int x = (n0 >> 6) & 7;

    // ---- stage 3 full P1 planes (swizzled: unit ^ (row&15)); 3072 uint4 ----
#pragma unroll
    for (int i = 0; i < 3; i++) {
        int u = tid + i * 1024;
        int p = u >> 10, rem = u & 1023;
        int row = rem >> 4, unit = rem & 15;
        int xp = x + p - 1;
        if ((unsigned)xp < 8u) {
            const char* src = (const char*)Pb + (size_t)(n0 + (p - 1) * 64 + row) * 512 + unit * 16;
            *(uint4*)(sP1 + p * 16384 + row * 256 + ((unit ^ (row & 15)) << 4)) = *(const uint4*)src;
        }
    }
    // ---- stage B = eW2^T (swizzled); 2048 uint4 ----
#pragma unroll
    for (int i = 0; i < 2; i++) {
        int u = tid + i * 1024;
        int row = u >> 4, unit = u & 15;
        *(uint4*)(sB + row * 256 + ((unit ^ (row & 15)) << 4)) =
            *(const uint4*)(imgW2 + row * 256 + unit * 16);
    }
    __syncthreads();

    int rowbase = mt * 16 + l15;                    // 0..63 node in plane
    int ya = rowbase >> 3, za = rowbase & 7;

    float p2f[32], wf[32];
    const char* p2p = (const char*)Pb + (size_t)(n0 + rowbase) * 512 + 256;
#pragma unroll
    for (int ks = 0; ks < 4; ks++) {
        short8 s = *(const short8*)(p2p + ks * 64 + kg * 16);
#pragma unroll
        for (int i = 0; i < 8; i++) p2f[ks * 8 + i] = bf2f(s[i]);
        float4 a4 = *(const float4*)(w256f + ks * 32 + kg * 8);
        float4 b4 = *(const float4*)(w256f + ks * 32 + kg * 8 + 4);
        wf[ks*8+0]=a4.x; wf[ks*8+1]=a4.y; wf[ks*8+2]=a4.z; wf[ks*8+3]=a4.w;
        wf[ks*8+4]=b4.x; wf[ks*8+5]=b4.y; wf[ks*8+6]=b4.z; wf[ks*8+7]=b4.w;
    }
    float b2v[8];
#pragma unroll
    for (int nt = 0; nt < 8; nt++) b2v[nt] = b2[nt * 16 + l15];

    float accag[8][4];
#pragma unroll
    for (int nt = 0; nt < 8; nt++)
#pragma unroll
        for (int r = 0; r < 4; r++) accag[nt][r] = 0.0f;

    int ye = mt * 2 + (kg >> 1), ze = (kg & 1) * 4;

    for (int o = grp; o < 26; o += 4) {
        int dx = SDX[o], dy = SDY[o], dz = SDZ[o];
        if ((unsigned)(x + dx) >= 8u) continue;
        float d = sqrtf((float)(4 * (dx * dx + dy * dy + dz * dz)));
        bool va = ((unsigned)(ya + dy) < 8u) & ((unsigned)(za + dz) < 8u);
        int rowr = va ? (rowbase + dy * 8 + dz) : rowbase;
        const char* ap = sP1 + (dx + 1) * 16384 + rowr * 256;
        int rsw = rowr & 15;

        f32x4 c[8];
#pragma unroll
        for (int nt = 0; nt < 8; nt++) { f32x4 z4 = {0.f,0.f,0.f,0.f}; c[nt] = z4; }
#pragma unroll
        for (int ks = 0; ks < 4; ks++) {
            short8 s = *(const short8*)(ap + (((ks * 4 + kg) ^ rsw) << 4));
            float vv[8];
#pragma unroll
            for (int i = 0; i < 8; i++) {
                float v = bf2f(s[i]) + p2f[ks * 8 + i] + d * wf[ks * 8 + i];
                vv[i] = silu_fast(v);
            }
            short8 a = pack_bf16_8(vv);
            __builtin_amdgcn_s_setprio(1);
#pragma unroll
            for (int nt = 0; nt < 8; nt++) {
                int brow = nt * 16 + l15;
                short8 b = *(const short8*)(sB + brow * 256 + (((ks * 4 + kg) ^ l15) << 4));
                c[nt] = __builtin_amdgcn_mfma_f32_16x16x32_bf16(a, b, c[nt], 0, 0, 0);
            }
            __builtin_amdgcn_s_setprio(0);
        }
#pragma unroll
        for (int r = 0; r < 4; r++) {
            bool vr = ((unsigned)(ye + dy) < 8u) & ((unsigned)(ze + r + dz) < 8u);
#pragma unroll
            for (int nt = 0; nt < 8; nt++) {
                float v = silu_fast(c[nt][r] + b2v[nt]);
                accag[nt][r] += vr ? v : 0.0f;
            }
        }
    }

    // ---- 4-group barrier-sequenced reduce into red (sP1; planes dead) ----
    __syncthreads();
    if (grp == 0) {
#pragma unroll
        for (int nt = 0; nt < 8; nt++)
#pragma unroll
            for (int r = 0; r < 4; r++)
                red[(mt * 16 + kg * 4 + r) * RSTR + nt * 16 + l15] = accag[nt][r];
    }
    __syncthreads();
    if (grp == 1) {
#pragma unroll
        for (int nt = 0; nt < 8; nt++)
#pragma unroll
            for (int r = 0; r < 4; r++)
                red[(mt * 16 + kg * 4 + r) * RSTR + nt * 16 + l15] += accag[nt][r];
    }
    __syncthreads();
    if (grp == 2) {
#pragma unroll
        for (int nt = 0; nt < 8; nt++)
#pragma unroll
            for (int r = 0; r < 4; r++)
                red[(mt * 16 + kg * 4 + r) * RSTR + nt * 16 + l15] += accag[nt][r];
    }
    __syncthreads();
    if (grp == 3) {
#pragma unroll
        for (int nt = 0; nt < 8; nt++)
#pragma unroll
            for (int r = 0; r < 4; r++)
                red[(mt * 16 + kg * 4 + r) * RSTR + nt * 16 + l15] += accag[nt][r];
    }
    __syncthreads();

    // ---- node MLP GEMM1: A = [hn | red*dinv]; nt tiles = grp+4t ----
    int nodeA = n0 + rowbase;
    int yA = (nodeA >> 3) & 7, zA = nodeA & 7;
    float dinvA = 1.0f / (float)((1 + (x > 0) + (x < 7)) * (1 + (yA > 0) + (yA < 7))
                                 * (1 + (zA > 0) + (zA < 7)) - 1);
    const float* hnr = hn + (size_t)nodeA * H;
    f32x4 acc1[2];
    { f32x4 z = {0.f,0.f,0.f,0.f}; acc1[0] = z; acc1[1] = z; }
#pragma unroll
    for (int ks = 0; ks < 8; ks++) {
        short8 a;
        if (ks < 4) a = cvtfrag(hnr + ks * 32 + kg * 8);
        else {
            float vv[8];
            const float* rp = red + rowbase * RSTR + (ks - 4) * 32 + kg * 8;
#pragma unroll
            for (int i = 0; i < 8; i++) vv[i] = rp[i] * dinvA;
            a = pack_bf16_8(vv);
        }
        const char* bp = imgN1 + ks * 64 + kg * 16;
#pragma unroll
        for (int t = 0; t < 2; t++) {
            int nt = grp + 4 * t;
            short8 b = *(const short8*)(bp + (nt * 16 + l15) * 512);
            acc1[t] = __builtin_amdgcn_mfma_f32_16x16x32_bf16(a, b, acc1[t], 0, 0, 0);
        }
    }
#pragma unroll
    for (int t = 0; t < 2; t++) {
        int nt = grp + 4 * t;
        int cc = nt * 16 + l15;
        float bb = nb1[cc];
#pragma unroll
        for (int r = 0; r < 4; r++) {
            float v = silu_fast(acc1[t][r] + bb);
            *(unsigned short*)(sM + (mt * 16 + kg * 4 + r) * 272 + cc * 2) = f2bf(v);
        }
    }
    __syncthreads();

    // ---- GEMM2 + residual; h2 overwrites red ----
    f32x4 acc2[2];
    { f32x4 z = {0.f,0.f,0.f,0.f}; acc2[0] = z; acc2[1] = z; }
#pragma unroll
    for (int ks = 0; ks < 4; ks++) {
        short8 a = *(const short8*)(sM + rowbase * 272 + ks * 64 + kg * 16);
        const char* bp = imgN2 + ks * 64 + kg * 16;
#pragma unroll
        for (int t = 0; t < 2; t++) {
            int nt = grp + 4 * t;
            short8 b = *(const short8*)(bp + (nt * 16 + l15) * 256);
            acc2[t] = __builtin_amdgcn_mfma_f32_16x16x32_bf16(a, b, acc2[t], 0, 0, 0);
        }
    }
#pragma unroll
    for (int t = 0; t < 2; t++) {
        int nt = grp + 4 * t;
        int cc = nt * 16 + l15;
        float bb = nb2[cc];
#pragma unroll
        for (int r = 0; r < 4; r++) {
            int rr = mt * 16 + kg * 4 + r;
            size_t gi = (size_t)(n0 + rr) * H + cc;
            float v = hn[gi] + acc2[t][r] + bb;
            if (last) h[gi] = v;
            else      h2[rr * RSTR + cc] = v;
        }
    }
    if (last) return;
    __syncthreads();

    // ---- LN(h') + next-layer P GEMM (row-local; LN dup across grp) ----
    float hv[32];
    const float* h2r = h2 + rowbase * RSTR;
#pragma unroll
    for (int ks = 0; ks < 4; ks++) {
#pragma unroll
        for (int i = 0; i < 8; i++) hv[ks * 8 + i] = h2r[ks * 32 + kg * 8 + i];
    }
    float s = 0.0f;
#pragma unroll
    for (int i = 0; i < 32; i++) s += hv[i];
    s += __shfl_xor(s, 16); s += __shfl_xor(s, 32);
    float mu = s * (1.0f / 128.0f);
    float vs = 0.0f;
#pragma unroll
    for (int i = 0; i < 32; i++) { float d = hv[i] - mu; vs += d * d; }
    vs += __shfl_xor(vs, 16); vs += __shfl_xor(vs, 32);
    float rsq = rsqrtf(vs * (1.0f / 128.0f) + 1e-5f);
#pragma unroll
    for (int ks = 0; ks < 4; ks++) {
        float4 g0 = *(const float4*)(lngn + ks * 32 + kg * 8);
        float4 g1 = *(const float4*)(lngn + ks * 32 + kg * 8 + 4);
        float4 c0 = *(const float4*)(lnbn + ks * 32 + kg * 8);
        float4 c1 = *(const float4*)(lnbn + ks * 32 + kg * 8 + 4);
        hv[ks*8+0] = (hv[ks*8+0]-mu)*rsq*g0.x + c0.x;
        hv[ks*8+1] = (hv[ks*8+1]-mu)*rsq*g0.y + c0.y;
        hv[ks*8+2] = (hv[ks*8+2]-mu)*rsq*g0.z + c0.z;
        hv[ks*8+3] = (hv[ks*8+3]-mu)*rsq*g0.w + c0.w;
        hv[ks*8+4] = (hv[ks*8+4]-mu)*rsq*g1.x + c1.x;
        hv[ks*8+5] = (hv[ks*8+5]-mu)*rsq*g1.y + c1.y;
        hv[ks*8+6] = (hv[ks*8+6]-mu)*rsq*g1.z + c1.z;
        hv[ks*8+7] = (hv[ks*8+7]-mu)*rsq*g1.w + c1.w;
    }
    if (grp == 0) {
        float* o = hn + (size_t)nodeA * H;
#pragma unroll
        for (int ks = 0; ks < 4; ks++) {
            *(float4*)(o + ks * 32 + kg * 8)     = *(float4*)&hv[ks*8];
            *(float4*)(o + ks * 32 + kg * 8 + 4) = *(float4*)&hv[ks*8+4];
        }
    }
    short8 aF[4];
#pragma unroll
    for (int ks = 0; ks < 4; ks++) aF[ks] = pack_bf16_8(&hv[ks*8]);
    f32x4 accP[4];
#pragma unroll
    for (int t = 0; t < 4; t++) { f32x4 z = {0.f,0.f,0.f,0.f}; accP[t] = z; }
#pragma unroll
    for (int ks = 0; ks < 4; ks++) {
        const char* bp = imgPn + ks * 64 + kg * 16;
#pragma unroll
        for (int t = 0; t < 4; t++) {
            int jt = grp + 4 * t;
            short8 b = *(const short8*)(bp + (jt * 16 + l15) * 256);
            accP[t] = __builtin_amdgcn_mfma_f32_16x16x32_bf16(aF[ks], b, accP[t], 0, 0, 0);
        }
    }
#pragma unroll
    for (int t = 0; t < 4; t++) {
        int jt = grp + 4 * t;
        int jj = jt * 16 + l15;
        float add = (jj >= 128) ? b1n[jj - 128] : 0.0f;
#pragma unroll
        for (int r = 0; r < 4; r++)
            PbOut[(size_t)(n0 + mt * 16 + kg * 4 + r) * 256 + jj] = f2bf(accP[t][r] + add);
    }
}

// ---------------- out = h @ W_out + b_out (MFMA, N-parallel) ----------------
__global__ __launch_bounds__(256) void k_out_mfma(const float* __restrict__ h,
                                                  const char* __restrict__ imgWout,
                                                  const float* __restrict__ bo,
                                                  float* __restrict__ out) {
    int bid = blockIdx.x;
    int rowblk = bid >> 3, nc = bid & 7;
    int tid = threadIdx.x, w = tid >> 6, lane = tid & 63;
    int l15 = lane & 15, kg = lane >> 4;
    int m0 = rowblk * 64 + w * 16;
    const float* hr = h + (size_t)(m0 + l15) * H;
    short8 a[4];
#pragma unroll
    for (int ks = 0; ks < 4; ks++) a[ks] = cvtfrag(hr + ks * 32 + kg * 8);
    f32x4 acc[8];
#pragma unroll
    for (int nt = 0; nt < 8; nt++) { f32x4 z = {0.f,0.f,0.f,0.f}; acc[nt] = z; }
#pragma unroll
    for (int ks = 0; ks < 4; ks++) {
        const char* bp = imgWout + (size_t)(nc * 128) * 256 + ks * 64 + kg * 16;
#pragma unroll
        for (int nt = 0; nt < 8; nt++) {
            short8 b = *(const short8*)(bp + (nt * 16 + l15) * 256);
            acc[nt] = __builtin_amdgcn_mfma_f32_16x16x32_bf16(a[ks], b, acc[nt], 0, 0, 0);
        }
    }
#pragma unroll
    for (int nt = 0; nt < 8; nt++) {
        int cc = nc * 128 + nt * 16 + l15;
        float bb = bo[cc];
#pragma unroll
        for (int r = 0; r < 4; r++)
            out[(size_t)(m0 + kg * 4 + r) * 1024 + cc] = acc[nt][r] + bb;
    }
}

extern "C" void kernel_launch(void* const* d_in, const int* in_sizes, int n_in,
                              void* d_out, int out_size, void* d_ws, size_t ws_size,
                              hipStream_t stream) {
    const float* y     = (const float*)d_in[0];
    const float* W_in  = (const float*)d_in[3];
    const float* b_in  = (const float*)d_in[4];
    const float* ln_g  = (const float*)d_in[5];
    const float* ln_b  = (const float*)d_in[6];
    const float* eW1   = (const float*)d_in[7];
    const float* eb1   = (const float*)d_in[8];
    const float* eW2   = (const float*)d_in[9];
    const float* eb2   = (const float*)d_in[10];
    const float* nW1   = (const float*)d_in[11];
    const float* nb1   = (const float*)d_in[12];
    const float* nW2   = (const float*)d_in[13];
    const float* nb2   = (const float*)d_in[14];
    const float* W_out = (const float*)d_in[15];
    const float* b_out = (const float*)d_in[16];

    char* wsb = (char*)d_ws;
    float* h    = (float*)(wsb + OFF_H);
    float* hn   = (float*)(wsb + OFF_HN);
    unsigned short* PbA = (unsigned short*)(wsb + OFF_PBUF);
    unsigned short* PbB = PbA + 4194304;   // 8 MB each

    k_prep<<<655360 / 256, 256, 0, stream>>>(W_in, W_out, eW1, nW1, nW2, eW2, wsb);
    k_in_mfma<<<NN / 64, 256, 0, stream>>>(y, wsb + OFF_WIN, b_in, h);
    k_lnP<<<NN / 64 * 2, 256, 0, stream>>>(h, ln_g, ln_b, wsb + OFF_P, eb1, hn, PbA);
    for (int l = 0; l < 4; ++l) {
        const unsigned short* Pin = (l & 1) ? PbB : PbA;
        unsigned short* Pout      = (l & 1) ? PbA : PbB;
        int last = (l == 3);
        int ln = last ? 0 : (l + 1);
        k_layer<<<NN / 64, 1024, 0, stream>>>(
            Pin, wsb + OFF_W2 + (size_t)l * 32768,
            eW1 + (size_t)l * 257 * H + 256 * H, eb2 + l * H,
            hn, wsb + OFF_N1 + (size_t)l * 65536, nb1 + l * H,
            wsb + OFF_N2 + (size_t)l * 32768, nb2 + l * H,
            h, last,
            ln_g + ln * H, ln_b + ln * H,
            wsb + OFF_P + (size_t)ln * 65536, eb1 + ln * H, Pout);
    }
    k_out_mfma<<<NN / 64 * 8, 256, 0, stream>>>(h, wsb + OFF_WOUT, b_out, (float*)d_out);
}

// Round 18
// 441.035 us; speedup vs baseline: 1.3166x; 1.3166x over previous
//
#include <hip/hip_runtime.h>
#include <math.h>

#define NN 16384
#define H 128
#define CODE 1024
#define RSTR 132   // f32 red/h2 stride: 132 mod 32 = 4 -> 2-way max bank aliasing

typedef __attribute__((ext_vector_type(8))) short short8;
typedef __attribute__((ext_vector_type(4))) float f32x4;

// ---- ws layout (bytes) ----
#define OFF_WIN   0u
#define OFF_WOUT  262144u
#define OFF_P     524288u       // 4 x [256][128] bf16 (eW1 split), stride 256
#define OFF_N1    786432u       // 4 x [128][256] bf16, stride 512
#define OFF_N2    1048576u      // 4 x [128][128] bf16, stride 256
#define OFF_W2    1179648u      // 4 x [128][128] bf16 eW2^T, stride 256
#define OFF_H     1318912u                   // h   fp32  8388608
#define OFF_HN    (OFF_H + 8388608u)         // hn  fp32  8388608
#define OFF_PBUF  (OFF_HN + 8388608u)        // Pb ping-pong: 2 x 8388608 bf16

__device__ __forceinline__ float silu_fast(float x) {
    float e = __expf(-x);
    return x * __builtin_amdgcn_rcpf(1.0f + e);
}

__device__ __forceinline__ unsigned short f2bf(float f) {
    unsigned int u = __float_as_uint(f);
    u = (u + 0x7FFFu + ((u >> 16) & 1u)) >> 16;
    return (unsigned short)u;
}

__device__ __forceinline__ float bf2f(short s) {
    return __uint_as_float(((unsigned)(unsigned short)s) << 16);
}

__device__ __forceinline__ short8 pack_bf16_8(const float* v) {
    union { unsigned u[4]; short8 s; } r;
    asm("v_cvt_pk_bf16_f32 %0, %1, %2" : "=v"(r.u[0]) : "v"(v[0]), "v"(v[1]));
    asm("v_cvt_pk_bf16_f32 %0, %1, %2" : "=v"(r.u[1]) : "v"(v[2]), "v"(v[3]));
    asm("v_cvt_pk_bf16_f32 %0, %1, %2" : "=v"(r.u[2]) : "v"(v[4]), "v"(v[5]));
    asm("v_cvt_pk_bf16_f32 %0, %1, %2" : "=v"(r.u[3]) : "v"(v[6]), "v"(v[7]));
    return r.s;
}

__device__ __forceinline__ short8 cvtfrag(const float* p) {
    float v[8];
    float4 a = *(const float4*)p;
    float4 b = *(const float4*)(p + 4);
    v[0]=a.x; v[1]=a.y; v[2]=a.z; v[3]=a.w; v[4]=b.x; v[5]=b.y; v[6]=b.z; v[7]=b.w;
    return pack_bf16_8(v);
}

__device__ const int SDX[26] = {-1,-1,-1,-1, 1, 1, 1, 1,  -1,-1,-1,-1, 0,  0, 0, 0, 1, 1, 1, 1,  -1, 1, 0, 0, 0, 0};
__device__ const int SDY[26] = {-1,-1, 1, 1,-1,-1, 1, 1,  -1, 0, 0, 1,-1, -1, 1, 1,-1, 0, 0, 1,   0, 0,-1, 1, 0, 0};
__device__ const int SDZ[26] = {-1, 1,-1, 1,-1, 1,-1, 1,   0,-1, 1, 0,-1,  1,-1, 1, 0,-1, 1, 0,   0, 0, 0, 0,-1, 1};

// transposed bf16 weight images
__global__ void k_prep(const float* __restrict__ W_in, const float* __restrict__ W_out,
                       const float* __restrict__ eW1, const float* __restrict__ nW1,
                       const float* __restrict__ nW2, const float* __restrict__ eW2,
                       char* __restrict__ base) {
    int t = blockIdx.x * 256 + threadIdx.x;
    if (t < 131072) {
        int n = t >> 10, k = t & 1023;
        *(unsigned short*)(base + OFF_WIN + n * 2048 + k * 2) = f2bf(W_in[k * 128 + n]);
        return;
    }
    t -= 131072;
    if (t < 131072) {
        int n = t >> 7, k = t & 127;
        *(unsigned short*)(base + OFF_WOUT + n * 256 + k * 2) = f2bf(W_out[k * 1024 + n]);
        return;
    }
    t -= 131072;
    if (t < 131072) {
        int l = t >> 15, r = t & 32767;
        int jj = r >> 7, k = r & 127;
        const float* W = eW1 + (size_t)l * 257 * 128;
        float v = (jj < 128) ? W[k * 128 + jj] : W[(128 + k) * 128 + (jj - 128)];
        *(unsigned short*)(base + OFF_P + (size_t)l * 65536 + jj * 256 + k * 2) = f2bf(v);
        return;
    }
    t -= 131072;
    if (t < 131072) {
        int l = t >> 15, r = t & 32767;
        int n = r >> 8, k = r & 255;
        *(unsigned short*)(base + OFF_N1 + (size_t)l * 65536 + n * 512 + k * 2) =
            f2bf(nW1[(size_t)l * 256 * 128 + k * 128 + n]);
        return;
    }
    t -= 131072;
    if (t < 65536) {
        int l = t >> 14, r = t & 16383;
        int n = r >> 7, k = r & 127;
        *(unsigned short*)(base + OFF_N2 + (size_t)l * 32768 + n * 256 + k * 2) =
            f2bf(nW2[(size_t)l * 128 * 128 + k * 128 + n]);
        return;
    }
    t -= 65536;
    if (t < 65536) {
        int l = t >> 14, r = t & 16383;
        int n = r >> 7, k = r & 127;
        *(unsigned short*)(base + OFF_W2 + (size_t)l * 32768 + n * 256 + k * 2) =
            f2bf(eW2[(size_t)l * 128 * 128 + k * 128 + n]);
    }
}

// ---------------- h = y @ W_in + b_in (MFMA) ----------------
__global__ __launch_bounds__(256) void k_in_mfma(const float* __restrict__ y,
                                                 const char* __restrict__ imgWin,
                                                 const float* __restrict__ bi,
                                                 float* __restrict__ h) {
    int tid = threadIdx.x, w = tid >> 6, lane = tid & 63;
    int l15 = lane & 15, kg = lane >> 4;
    int m0 = blockIdx.x * 64 + w * 16;
    const float* yr = y + (size_t)(m0 + l15) * CODE;
    f32x4 acc[8];
#pragma unroll
    for (int nt = 0; nt < 8; nt++) { f32x4 z = {0.f,0.f,0.f,0.f}; acc[nt] = z; }
#pragma unroll 4
    for (int ks = 0; ks < 32; ks++) {
        short8 a = cvtfrag(yr + ks * 32 + kg * 8);
        const char* bp = imgWin + ks * 64 + kg * 16;
#pragma unroll
        for (int nt = 0; nt < 8; nt++) {
            short8 b = *(const short8*)(bp + (nt * 16 + l15) * 2048);
            acc[nt] = __builtin_amdgcn_mfma_f32_16x16x32_bf16(a, b, acc[nt], 0, 0, 0);
        }
    }
#pragma unroll
    for (int nt = 0; nt < 8; nt++) {
        int cc = nt * 16 + l15;
        float bb = bi[cc];
#pragma unroll
        for (int r = 0; r < 4; r++)
            h[(size_t)(m0 + kg * 4 + r) * H + cc] = acc[nt][r] + bb;
    }
}

// ---------------- fused LN + P GEMM (layer 0 only) ----------------
__global__ __launch_bounds__(256) void k_lnP(const float* __restrict__ h,
                                             const float* __restrict__ g,
                                             const float* __restrict__ bln,
                                             const char* __restrict__ imgP,
                                             const float* __restrict__ b1,
                                             float* __restrict__ hn,
                                             unsigned short* __restrict__ Pb) {
    int bid = blockIdx.x;
    int rowblk = bid >> 1, nc = bid & 1;
    int tid = threadIdx.x, w = tid >> 6, lane = tid & 63;
    int l15 = lane & 15, kg = lane >> 4;
    int m0 = rowblk * 64 + w * 16;
    int row = m0 + l15;
    const float* hr = h + (size_t)row * H;

    float hv[32];
#pragma unroll
    for (int ks = 0; ks < 4; ks++) {
        float4 a4 = *(const float4*)(hr + ks * 32 + kg * 8);
        float4 b4 = *(const float4*)(hr + ks * 32 + kg * 8 + 4);
        hv[ks*8+0]=a4.x; hv[ks*8+1]=a4.y; hv[ks*8+2]=a4.z; hv[ks*8+3]=a4.w;
        hv[ks*8+4]=b4.x; hv[ks*8+5]=b4.y; hv[ks*8+6]=b4.z; hv[ks*8+7]=b4.w;
    }
    float s = 0.0f;
#pragma unroll
    for (int i = 0; i < 32; i++) s += hv[i];
    s += __shfl_xor(s, 16); s += __shfl_xor(s, 32);
    float mu = s * (1.0f / 128.0f);
    float vs = 0.0f;
#pragma unroll
    for (int i = 0; i < 32; i++) { float d = hv[i] - mu; vs += d * d; }
    vs += __shfl_xor(vs, 16); vs += __shfl_xor(vs, 32);
    float rs = rsqrtf(vs * (1.0f / 128.0f) + 1e-5f);

#pragma unroll
    for (int ks = 0; ks < 4; ks++) {
        float4 g0 = *(const float4*)(g + ks * 32 + kg * 8);
        float4 g1 = *(const float4*)(g + ks * 32 + kg * 8 + 4);
        float4 c0 = *(const float4*)(bln + ks * 32 + kg * 8);
        float4 c1 = *(const float4*)(bln + ks * 32 + kg * 8 + 4);
        hv[ks*8+0] = (hv[ks*8+0]-mu)*rs*g0.x + c0.x;
        hv[ks*8+1] = (hv[ks*8+1]-mu)*rs*g0.y + c0.y;
        hv[ks*8+2] = (hv[ks*8+2]-mu)*rs*g0.z + c0.z;
        hv[ks*8+3] = (hv[ks*8+3]-mu)*rs*g0.w + c0.w;
        hv[ks*8+4] = (hv[ks*8+4]-mu)*rs*g1.x + c1.x;
        hv[ks*8+5] = (hv[ks*8+5]-mu)*rs*g1.y + c1.y;
        hv[ks*8+6] = (hv[ks*8+6]-mu)*rs*g1.z + c1.z;
        hv[ks*8+7] = (hv[ks*8+7]-mu)*rs*g1.w + c1.w;
    }
    if (nc == 0) {
        float* o = hn + (size_t)row * H;
#pragma unroll
        for (int ks = 0; ks < 4; ks++) {
            *(float4*)(o + ks * 32 + kg * 8)     = *(float4*)&hv[ks*8];
            *(float4*)(o + ks * 32 + kg * 8 + 4) = *(float4*)&hv[ks*8+4];
        }
    }
    short8 a[4];
#pragma unroll
    for (int ks = 0; ks < 4; ks++) a[ks] = pack_bf16_8(&hv[ks*8]);

    f32x4 acc[8];
#pragma unroll
    for (int nt = 0; nt < 8; nt++) { f32x4 z = {0.f,0.f,0.f,0.f}; acc[nt] = z; }
#pragma unroll
    for (int ks = 0; ks < 4; ks++) {
        const char* bp = imgP + (size_t)(nc * 128) * 256 + ks * 64 + kg * 16;
#pragma unroll
        for (int nt = 0; nt < 8; nt++) {
            short8 b = *(const short8*)(bp + (nt * 16 + l15) * 256);
            acc[nt] = __builtin_amdgcn_mfma_f32_16x16x32_bf16(a[ks], b, acc[nt], 0, 0, 0);
        }
    }
#pragma unroll
    for (int nt = 0; nt < 8; nt++) {
        int jj = nc * 128 + nt * 16 + l15;
        float add = nc ? b1[nt * 16 + l15] : 0.0f;
#pragma unroll
        for (int r = 0; r < 4; r++)
            Pb[(size_t)(m0 + kg * 4 + r) * 256 + jj] = f2bf(acc[nt][r] + add);
    }
}

// ---------------- FUSED LAYER: full-plane block, 12 waves (4 M-tiles x 3 groups) ----------------
// grid = 256 = 1 block/CU; 3 waves/SIMD. Branchless offset loop (unroll 2 for ILP).
__global__ __launch_bounds__(768) void k_layer(
        const unsigned short* __restrict__ Pb, const char* __restrict__ imgW2,
        const float* __restrict__ w256f, const float* __restrict__ b2,
        float* __restrict__ hn, const char* __restrict__ imgN1,
        const float* __restrict__ nb1, const char* __restrict__ imgN2,
        const float* __restrict__ nb2, float* __restrict__ h, int last,
        const float* __restrict__ lngn, const float* __restrict__ lnbn,
        const char* __restrict__ imgPn, const float* __restrict__ b1n,
        unsigned short* __restrict__ PbOut) {
    __shared__ __align__(16) char sP1[3 * 16384];   // planes -> red f32 -> h2 f32
    __shared__ __align__(16) char sB[32768];        // eW2 -> sM bf16
    float* red = (float*)sP1;
    float* h2  = (float*)sP1;
    char*  sM  = sB;

    int tid = threadIdx.x, wv = tid >> 6, lane = tid & 63;
    int mt = wv & 3, grp = wv >> 2;                 // mt 0..3, grp 0..2
    int l15 = lane & 15, kg = lane >> 4;
    int n0 = blockIdx.x * 64;
    int x = (n0 >> 6) & 7;

    // ---- stage 3 full P1 planes (swizzled: unit ^ (row&15)); 3072 uint4 ----
#pragma unroll
    for (int i = 0; i < 4; i++) {
        int u = tid + i * 768;
        int p = u >> 10, rem = u & 1023;
        int row = rem >> 4, unit = rem & 15;
        int xp = x + p - 1;
        if ((unsigned)xp < 8u) {
            const char* src = (const char*)Pb + (size_t)(n0 + (p - 1) * 64 + row) * 512 + unit * 16;
            *(uint4*)(sP1 + p * 16384 + row * 256 + ((unit ^ (row & 15)) << 4)) = *(const uint4*)src;
        }
    }
    // ---- stage B = eW2^T (swizzled); 2048 uint4 ----
#pragma unroll
    for (int i = 0; i < 3; i++) {
        int u = tid + i * 768;
        if (u < 2048) {
            int row = u >> 4, unit = u & 15;
            *(uint4*)(sB + row * 256 + ((unit ^ (row & 15)) << 4)) =
                *(const uint4*)(imgW2 + row * 256 + unit * 16);
        }
    }
    __syncthreads();

    int rowbase = mt * 16 + l15;                    // 0..63 node in plane
    int ya = rowbase >> 3, za = rowbase & 7;

    float p2f[32], wf[32];
    const char* p2p = (const char*)Pb + (size_t)(n0 + rowbase) * 512 + 256;
#pragma unroll
    for (int ks = 0; ks < 4; ks++) {
        short8 s = *(const short8*)(p2p + ks * 64 + kg * 16);
#pragma unroll
        for (int i = 0; i < 8; i++) p2f[ks * 8 + i] = bf2f(s[i]);
        float4 a4 = *(const float4*)(w256f + ks * 32 + kg * 8);
        float4 b4 = *(const float4*)(w256f + ks * 32 + kg * 8 + 4);
        wf[ks*8+0]=a4.x; wf[ks*8+1]=a4.y; wf[ks*8+2]=a4.z; wf[ks*8+3]=a4.w;
        wf[ks*8+4]=b4.x; wf[ks*8+5]=b4.y; wf[ks*8+6]=b4.z; wf[ks*8+7]=b4.w;
    }
    float b2v[8];
#pragma unroll
    for (int nt = 0; nt < 8; nt++) b2v[nt] = b2[nt * 16 + l15];

    float accag[8][4];
#pragma unroll
    for (int nt = 0; nt < 8; nt++)
#pragma unroll
        for (int r = 0; r < 4; r++) accag[nt][r] = 0.0f;

    int ye = mt * 2 + (kg >> 1), ze = (kg & 1) * 4;

    // branchless offset loop: x-validity folded into the accumulate mask (vx);
    // unstaged-halo reads yield garbage that is cndmask'ed to exact 0.
#pragma unroll 2
    for (int o = grp; o < 26; o += 3) {
        int dx = SDX[o], dy = SDY[o], dz = SDZ[o];
        bool vx = ((unsigned)(x + dx) < 8u);
        float d = sqrtf((float)(4 * (dx * dx + dy * dy + dz * dz)));
        bool va = ((unsigned)(ya + dy) < 8u) & ((unsigned)(za + dz) < 8u);
        int rowr = va ? (rowbase + dy * 8 + dz) : rowbase;
        const char* ap = sP1 + (dx + 1) * 16384 + rowr * 256;
        int rsw = rowr & 15;

        f32x4 c[8];
#pragma unroll
        for (int nt = 0; nt < 8; nt++) { f32x4 z4 = {0.f,0.f,0.f,0.f}; c[nt] = z4; }
#pragma unroll
        for (int ks = 0; ks < 4; ks++) {
            short8 s = *(const short8*)(ap + (((ks * 4 + kg) ^ rsw) << 4));
            float vv[8];
#pragma unroll
            for (int i = 0; i < 8; i++) {
                float v = bf2f(s[i]) + p2f[ks * 8 + i] + d * wf[ks * 8 + i];
                vv[i] = silu_fast(v);
            }
            short8 a = pack_bf16_8(vv);
            __builtin_amdgcn_s_setprio(1);
#pragma unroll
            for (int nt = 0; nt < 8; nt++) {
                int brow = nt * 16 + l15;
                short8 b = *(const short8*)(sB + brow * 256 + (((ks * 4 + kg) ^ l15) << 4));
                c[nt] = __builtin_amdgcn_mfma_f32_16x16x32_bf16(a, b, c[nt], 0, 0, 0);
            }
            __builtin_amdgcn_s_setprio(0);
        }
#pragma unroll
        for (int r = 0; r < 4; r++) {
            bool vr = vx & ((unsigned)(ye + dy) < 8u) & ((unsigned)(ze + r + dz) < 8u);
#pragma unroll
            for (int nt = 0; nt < 8; nt++) {
                float v = silu_fast(c[nt][r] + b2v[nt]);
                accag[nt][r] += vr ? v : 0.0f;
            }
        }
    }

    // ---- 3-group reduce into red (sP1; planes dead) ----
    __syncthreads();
    if (grp == 0) {
#pragma unroll
        for (int nt = 0; nt < 8; nt++)
#pragma unroll
            for (int r = 0; r < 4; r++)
                red[(mt * 16 + kg * 4 + r) * RSTR + nt * 16 + l15] = accag[nt][r];
    }
    __syncthreads();
    if (grp == 1) {
#pragma unroll
        for (int nt = 0; nt < 8; nt++)
#pragma unroll
            for (int r = 0; r < 4; r++)
                red[(mt * 16 + kg * 4 + r) * RSTR + nt * 16 + l15] += accag[nt][r];
    }
    __syncthreads();
    if (grp == 2) {
#pragma unroll
        for (int nt = 0; nt < 8; nt++)
#pragma unroll
            for (int r = 0; r < 4; r++)
                red[(mt * 16 + kg * 4 + r) * RSTR + nt * 16 + l15] += accag[nt][r];
    }
    __syncthreads();

    // ---- node MLP GEMM1: A = [hn | red*dinv]; nt tiles = grp+3t ----
    int nodeA = n0 + rowbase;
    int yA = (nodeA >> 3) & 7, zA = nodeA & 7;
    float dinvA = 1.0f / (float)((1 + (x > 0) + (x < 7)) * (1 + (yA > 0) + (yA < 7))
                                 * (1 + (zA > 0) + (zA < 7)) - 1);
    const float* hnr = hn + (size_t)nodeA * H;
    f32x4 acc1[3];
#pragma unroll
    for (int t = 0; t < 3; t++) { f32x4 z = {0.f,0.f,0.f,0.f}; acc1[t] = z; }
#pragma unroll
    for (int ks = 0; ks < 8; ks++) {
        short8 a;
        if (ks < 4) a = cvtfrag(hnr + ks * 32 + kg * 8);
        else {
            float vv[8];
            const float* rp = red + rowbase * RSTR + (ks - 4) * 32 + kg * 8;
#pragma unroll
            for (int i = 0; i < 8; i++) vv[i] = rp[i] * dinvA;
            a = pack_bf16_8(vv);
        }
        const char* bp = imgN1 + ks * 64 + kg * 16;
#pragma unroll
        for (int t = 0; t < 3; t++) {
            int nt = grp + 3 * t;
            if (nt < 8) {
                short8 b = *(const short8*)(bp + (nt * 16 + l15) * 512);
                acc1[t] = __builtin_amdgcn_mfma_f32_16x16x32_bf16(a, b, acc1[t], 0, 0, 0);
            }
        }
    }
#pragma unroll
    for (int t = 0; t < 3; t++) {
        int nt = grp + 3 * t;
        if (nt < 8) {
            int cc = nt * 16 + l15;
            float bb = nb1[cc];
#pragma unroll
            for (int r = 0; r < 4; r++) {
                float v = silu_fast(acc1[t][r] + bb);
                *(unsigned short*)(sM + (mt * 16 + kg * 4 + r) * 272 + cc * 2) = f2bf(v);
            }
        }
    }
    __syncthreads();

    // ---- GEMM2 + residual; h2 overwrites red ----
    f32x4 acc2[3];
#pragma unroll
    for (int t = 0; t < 3; t++) { f32x4 z = {0.f,0.f,0.f,0.f}; acc2[t] = z; }
#pragma unroll
    for (int ks = 0; ks < 4; ks++) {
        short8 a = *(const short8*)(sM + rowbase * 272 + ks * 64 + kg * 16);
        const char* bp = imgN2 + ks * 64 + kg * 16;
#pragma unroll
        for (int t = 0; t < 3; t++) {
            int nt = grp + 3 * t;
            if (nt < 8) {
                short8 b = *(const short8*)(bp + (nt * 16 + l15) * 256);
                acc2[t] = __builtin_amdgcn_mfma_f32_16x16x32_bf16(a, b, acc2[t], 0, 0, 0);
            }
        }
    }
#pragma unroll
    for (int t = 0; t < 3; t++) {
        int nt = grp + 3 * t;
        if (nt < 8) {
            int cc = nt * 16 + l15;
            float bb = nb2[cc];
#pragma unroll
            for (int r = 0; r < 4; r++) {
                int rr = mt * 16 + kg * 4 + r;
                size_t gi = (size_t)(n0 + rr) * H + cc;
                float v = hn[gi] + acc2[t][r] + bb;
                if (last) h[gi] = v;
                else      h2[rr * RSTR + cc] = v;
            }
        }
    }
    if (last) return;
    __syncthreads();

    // ---- LN(h') + next-layer P GEMM ----
    float hv[32];
    const float* h2r = h2 + rowbase * RSTR;
#pragma unroll
    for (int ks = 0; ks < 4; ks++) {
#pragma unroll
        for (int i = 0; i < 8; i++) hv[ks * 8 + i] = h2r[ks * 32 + kg * 8 + i];
    }
    float s = 0.0f;
#pragma unroll
    for (int i = 0; i < 32; i++) s += hv[i];
    s += __shfl_xor(s, 16); s += __shfl_xor(s, 32);
    float mu = s * (1.0f / 128.0f);
    float vs = 0.0f;
#pragma unroll
    for (int i = 0; i < 32; i++) { float d = hv[i] - mu; vs += d * d; }
    vs += __shfl_xor(vs, 16); vs += __shfl_xor(vs, 32);
    float rsq = rsqrtf(vs * (1.0f / 128.0f) + 1e-5f);
#pragma unroll
    for (int ks = 0; ks < 4; ks++) {
        float4 g0 = *(const float4*)(lngn + ks * 32 + kg * 8);
        float4 g1 = *(const float4*)(lngn + ks * 32 + kg * 8 + 4);
        float4 c0 = *(const float4*)(lnbn + ks * 32 + kg * 8);
        float4 c1 = *(const float4*)(lnbn + ks * 32 + kg * 8 + 4);
        hv[ks*8+0] = (hv[ks*8+0]-mu)*rsq*g0.x + c0.x;
        hv[ks*8+1] = (hv[ks*8+1]-mu)*rsq*g0.y + c0.y;
        hv[ks*8+2] = (hv[ks*8+2]-mu)*rsq*g0.z + c0.z;
        hv[ks*8+3] = (hv[ks*8+3]-mu)*rsq*g0.w + c0.w;
        hv[ks*8+4] = (hv[ks*8+4]-mu)*rsq*g1.x + c1.x;
        hv[ks*8+5] = (hv[ks*8+5]-mu)*rsq*g1.y + c1.y;
        hv[ks*8+6] = (hv[ks*8+6]-mu)*rsq*g1.z + c1.z;
        hv[ks*8+7] = (hv[ks*8+7]-mu)*rsq*g1.w + c1.w;
    }
    if (grp == 0) {
        float* o = hn + (size_t)nodeA * H;
#pragma unroll
        for (int ks = 0; ks < 4; ks++) {
            *(float4*)(o + ks * 32 + kg * 8)     = *(float4*)&hv[ks*8];
            *(float4*)(o + ks * 32 + kg * 8 + 4) = *(float4*)&hv[ks*8+4];
        }
    }
    short8 aF[4];
#pragma unroll
    for (int ks = 0; ks < 4; ks++) aF[ks] = pack_bf16_8(&hv[ks*8]);
    f32x4 accP[6];
#pragma unroll
    for (int t = 0; t < 6; t++) { f32x4 z = {0.f,0.f,0.f,0.f}; accP[t] = z; }
#pragma unroll
    for (int ks = 0; ks < 4; ks++) {
        const char* bp = imgPn + ks * 64 + kg * 16;
#pragma unroll
        for (int t = 0; t < 6; t++) {
            int jt = grp + 3 * t;
            if (jt < 16) {
                short8 b = *(const short8*)(bp + (jt * 16 + l15) * 256);
                accP[t] = __builtin_amdgcn_mfma_f32_16x16x32_bf16(aF[ks], b, accP[t], 0, 0, 0);
            }
        }
    }
#pragma unroll
    for (int t = 0; t < 6; t++) {
        int jt = grp + 3 * t;
        if (jt < 16) {
            int jj = jt * 16 + l15;
            float add = (jj >= 128) ? b1n[jj - 128] : 0.0f;
#pragma unroll
            for (int r = 0; r < 4; r++)
                PbOut[(size_t)(n0 + mt * 16 + kg * 4 + r) * 256 + jj] = f2bf(accP[t][r] + add);
        }
    }
}

// ---------------- out = h @ W_out + b_out (MFMA, N-parallel) ----------------
__global__ __launch_bounds__(256) void k_out_mfma(const float* __restrict__ h,
                                                  const char* __restrict__ imgWout,
                                                  const float* __restrict__ bo,
                                                  float* __restrict__ out) {
    int bid = blockIdx.x;
    int rowblk = bid >> 3, nc = bid & 7;
    int tid = threadIdx.x, w = tid >> 6, lane = tid & 63;
    int l15 = lane & 15, kg = lane >> 4;
    int m0 = rowblk * 64 + w * 16;
    const float* hr = h + (size_t)(m0 + l15) * H;
    short8 a[4];
#pragma unroll
    for (int ks = 0; ks < 4; ks++) a[ks] = cvtfrag(hr + ks * 32 + kg * 8);
    f32x4 acc[8];
#pragma unroll
    for (int nt = 0; nt < 8; nt++) { f32x4 z = {0.f,0.f,0.f,0.f}; acc[nt] = z; }
#pragma unroll
    for (int ks = 0; ks < 4; ks++) {
        const char* bp = imgWout + (size_t)(nc * 128) * 256 + ks * 64 + kg * 16;
#pragma unroll
        for (int nt = 0; nt < 8; nt++) {
            short8 b = *(const short8*)(bp + (nt * 16 + l15) * 256);
            acc[nt] = __builtin_amdgcn_mfma_f32_16x16x32_bf16(a[ks], b, acc[nt], 0, 0, 0);
        }
    }
#pragma unroll
    for (int nt = 0; nt < 8; nt++) {
        int cc = nc * 128 + nt * 16 + l15;
        float bb = bo[cc];
#pragma unroll
        for (int r = 0; r < 4; r++)
            out[(size_t)(m0 + kg * 4 + r) * 1024 + cc] = acc[nt][r] + bb;
    }
}

extern "C" void kernel_launch(void* const* d_in, const int* in_sizes, int n_in,
                              void* d_out, int out_size, void* d_ws, size_t ws_size,
                              hipStream_t stream) {
    const float* y     = (const float*)d_in[0];
    const float* W_in  = (const float*)d_in[3];
    const float* b_in  = (const float*)d_in[4];
    const float* ln_g  = (const float*)d_in[5];
    const float* ln_b  = (const float*)d_in[6];
    const float* eW1   = (const float*)d_in[7];
    const float* eb1   = (const float*)d_in[8];
    const float* eW2   = (const float*)d_in[9];
    const float* eb2   = (const float*)d_in[10];
    const float* nW1   = (const float*)d_in[11];
    const float* nb1   = (const float*)d_in[12];
    const float* nW2   = (const float*)d_in[13];
    const float* nb2   = (const float*)d_in[14];
    const float* W_out = (const float*)d_in[15];
    const float* b_out = (const float*)d_in[16];

    char* wsb = (char*)d_ws;
    float* h    = (float*)(wsb + OFF_H);
    float* hn   = (float*)(wsb + OFF_HN);
    unsigned short* PbA = (unsigned short*)(wsb + OFF_PBUF);
    unsigned short* PbB = PbA + 4194304;   // 8 MB each

    k_prep<<<655360 / 256, 256, 0, stream>>>(W_in, W_out, eW1, nW1, nW2, eW2, wsb);
    k_in_mfma<<<NN / 64, 256, 0, stream>>>(y, wsb + OFF_WIN, b_in, h);
    k_lnP<<<NN / 64 * 2, 256, 0, stream>>>(h, ln_g, ln_b, wsb + OFF_P, eb1, hn, PbA);
    for (int l = 0; l < 4; ++l) {
        const unsigned short* Pin = (l & 1) ? PbB : PbA;
        unsigned short* Pout      = (l & 1) ? PbA : PbB;
        int last = (l == 3);
        int ln = last ? 0 : (l + 1);
        k_layer<<<NN / 64, 768, 0, stream>>>(
            Pin, wsb + OFF_W2 + (size_t)l * 32768,
            eW1 + (size_t)l * 257 * H + 256 * H, eb2 + l * H,
            hn, wsb + OFF_N1 + (size_t)l * 65536, nb1 + l * H,
            wsb + OFF_N2 + (size_t)l * 32768, nb2 + l * H,
            h, last,
            ln_g + ln * H, ln_b + ln * H,
            wsb + OFF_P + (size_t)ln * 65536, eb1 + ln * H, Pout);
    }
    k_out_mfma<<<NN / 64 * 8, 256, 0, stream>>>(h, wsb + OFF_WOUT, b_out, (float*)d_out);
}